// Round 1
// baseline (2104.829 us; speedup 1.0000x reference)
//
#include <hip/hip_runtime.h>
#include <math.h>

#define T_LEN 32768
#define NB 4
#define NC 64
#define NL 18
#define TILE_T 64

// ------------------------------------------------------------------
// prep: input 1x1 conv, weight transposes (for coalesced LDS staging),
//       d_out init with mix_b
// ------------------------------------------------------------------
__global__ void prep_kernel(const float* __restrict__ x,
                            const float* __restrict__ in_w,
                            const float* __restrict__ in_b,
                            const float* __restrict__ hid_w,
                            const float* __restrict__ res_w,
                            const float* __restrict__ mix_b,
                            float* __restrict__ A0,
                            float* __restrict__ Wt,    // [L][3][64ci][128co]
                            float* __restrict__ WrT,   // [L][64ci][64co]
                            float* __restrict__ out)   // [B][T]
{
    const int nAct = NB * NC * T_LEN;          // 8388608
    const int nWt  = NL * 3 * NC * 128;        // 442368
    const int nWr  = NL * NC * NC;             // 73728
    const int nOut = NB * T_LEN;               // 131072
    const int total = nAct + nWt + nWr + nOut;
    for (int gid = blockIdx.x * blockDim.x + threadIdx.x; gid < total;
         gid += gridDim.x * blockDim.x) {
        if (gid < nAct) {
            int t = gid & (T_LEN - 1);
            int c = (gid >> 15) & (NC - 1);
            int b = gid >> 21;
            A0[gid] = x[b * T_LEN + t] * in_w[c] + in_b[c];
        } else if (gid < nAct + nWt) {
            int q = gid - nAct;
            int co = q & 127;
            int ci = (q >> 7) & 63;
            int ik = q >> 13;          // = i*3 + k
            int k  = ik % 3;
            int i  = ik / 3;
            // hid_w: [L][128co][64ci][3k]
            Wt[q] = hid_w[((i * 128 + co) * 64 + ci) * 3 + k];
        } else if (gid < nAct + nWt + nWr) {
            int q = gid - (nAct + nWt);
            int co = q & 63;
            int c  = (q >> 6) & 63;
            int i  = q >> 12;
            // res_w: [L][64co][64ci][1]
            WrT[q] = res_w[(i * 64 + co) * 64 + c];
        } else {
            int q = gid - (nAct + nWt + nWr);
            out[q] = mix_b[0];
        }
    }
}

// ------------------------------------------------------------------
// one WaveNet layer, fully fused:
//   h = dilated causal conv (128 out-ch), gated = tanh(hA)*sigmoid(hB),
//   actOut = res_conv(gated) + actIn, out += sum_c mix_w[c]*gated[c]
// block: 256 threads, covers (b, t0..t0+63, all channels)
// ------------------------------------------------------------------
__launch_bounds__(256, 3)
__global__ void layer_kernel(const float* __restrict__ actIn,
                             float* __restrict__ actOut,
                             const float* __restrict__ Wt,   // [3][64ci][128co]
                             const float* __restrict__ hb,   // [128]
                             const float* __restrict__ WrT,  // [64ci][64co]
                             const float* __restrict__ rb,   // [64]
                             const float* __restrict__ mw,   // [64]
                             float* __restrict__ skip,       // [B][T]
                             int dil)
{
    __shared__ float Xs[64 * 64];      // X tile for current tap; ends as inp tile
    __shared__ float Wb[128 * 64];     // W tap [ci][128co]; later WresT + Gs
    float* Gs = &Wb[4096];             // gated [64c][64t] (overlays upper half)

    const int tid = threadIdx.x;
    const int tx = tid & 15;           // t group  (4 t each)
    const int ty = tid >> 4;           // co group (4 pairs: c=ty*4+jj, c+64)
    const int b  = blockIdx.y;
    const int t0 = blockIdx.x * TILE_T;
    const float* actB = actIn + (size_t)b * NC * T_LEN;

    float acc[8][4];
#pragma unroll
    for (int j = 0; j < 8; j++)
#pragma unroll
        for (int q = 0; q < 4; q++) acc[j][q] = 0.f;

    for (int k = 0; k < 3; k++) {
        // ---- stage X tap tile: Xs[ci][tt] = act[ci][t0+tt+(k-2)*dil] ----
        const int toff = (k - 2) * dil;
#pragma unroll
        for (int r = 0; r < 16; r++) {
            int idx = r * 256 + tid;
            int ci = idx >> 6, tt = idx & 63;
            int st = t0 + tt + toff;
            Xs[idx] = (st >= 0) ? actB[ci * T_LEN + st] : 0.f;
        }
        // ---- stage W tap: Wb[ci*128 + co] ----
        const float* Wk = Wt + k * (64 * 128);
#pragma unroll
        for (int r = 0; r < 32; r++) {
            int idx = r * 256 + tid;
            Wb[idx] = Wk[idx];
        }
        __syncthreads();
        // ---- GEMM: acc[j][q] += W[ci][co(j)] * X[ci][t(q)] ----
#pragma unroll 8
        for (int ci = 0; ci < 64; ci++) {
            const float4 xv = *(const float4*)&Xs[ci * 64 + tx * 4];
            const float4 wa = *(const float4*)&Wb[ci * 128 + ty * 4];
            const float4 wc = *(const float4*)&Wb[ci * 128 + 64 + ty * 4];
            const float xr[4] = {xv.x, xv.y, xv.z, xv.w};
            const float wr[8] = {wa.x, wa.y, wa.z, wa.w, wc.x, wc.y, wc.z, wc.w};
#pragma unroll
            for (int j = 0; j < 8; j++)
#pragma unroll
                for (int q = 0; q < 4; q++)
                    acc[j][q] = fmaf(wr[j], xr[q], acc[j][q]);
        }
        __syncthreads();
    }

    // ---- gating (pairs c / c+64 live in same thread) ----
    float g[4][4];
#pragma unroll
    for (int jj = 0; jj < 4; jj++) {
        const int c = ty * 4 + jj;
        const float bA = hb[c];
        const float bB = hb[64 + c];
#pragma unroll
        for (int q = 0; q < 4; q++) {
            float hA = acc[jj][q] + bA;
            float hB = acc[jj + 4][q] + bB;
            g[jj][q] = tanhf(hA) * (1.f / (1.f + expf(-hB)));
        }
    }

    // Wb no longer needed (last sync already passed): write gated, stage Wres
#pragma unroll
    for (int jj = 0; jj < 4; jj++) {
        const int c = ty * 4 + jj;
        float4 gv = make_float4(g[jj][0], g[jj][1], g[jj][2], g[jj][3]);
        *(float4*)&Gs[c * 64 + tx * 4] = gv;
    }
#pragma unroll
    for (int r = 0; r < 16; r++) {
        int idx = r * 256 + tid;
        Wb[idx] = WrT[idx];            // lower 16KB of Wb
    }
    __syncthreads();

    // ---- res GEMM: acc2[jj][q] = sum_c WrT[c][co2]*g[c][t] ----
    float acc2[4][4];
#pragma unroll
    for (int j = 0; j < 4; j++)
#pragma unroll
        for (int q = 0; q < 4; q++) acc2[j][q] = 0.f;
#pragma unroll 8
    for (int c = 0; c < 64; c++) {
        const float4 xg = *(const float4*)&Gs[c * 64 + tx * 4];
        const float4 wv = *(const float4*)&Wb[c * 64 + ty * 4];
        const float xr[4] = {xg.x, xg.y, xg.z, xg.w};
        const float wr[4] = {wv.x, wv.y, wv.z, wv.w};
#pragma unroll
        for (int j = 0; j < 4; j++)
#pragma unroll
            for (int q = 0; q < 4; q++)
                acc2[j][q] = fmaf(wr[j], xr[q], acc2[j][q]);
    }

    // ---- skip reduction into out (one thread per t) ----
    if (tid < 64) {
        float s = 0.f;
#pragma unroll 8
        for (int c = 0; c < 64; c++) s += mw[c] * Gs[c * 64 + tid];
        skip[b * T_LEN + t0 + tid] += s;
    }

    // ---- epilogue: out = res + bias + inp (Xs still holds tap-2 = inp tile) ----
    float* outB = actOut + (size_t)b * NC * T_LEN;
#pragma unroll
    for (int jj = 0; jj < 4; jj++) {
        const int co = ty * 4 + jj;
        const float rbv = rb[co];
        const float4 inp = *(const float4*)&Xs[co * 64 + tx * 4];
        float4 o;
        o.x = acc2[jj][0] + rbv + inp.x;
        o.y = acc2[jj][1] + rbv + inp.y;
        o.z = acc2[jj][2] + rbv + inp.z;
        o.w = acc2[jj][3] + rbv + inp.w;
        *(float4*)&outB[co * T_LEN + t0 + tx * 4] = o;
    }
}

// ------------------------------------------------------------------
extern "C" void kernel_launch(void* const* d_in, const int* in_sizes, int n_in,
                              void* d_out, int out_size, void* d_ws, size_t ws_size,
                              hipStream_t stream) {
    const float* x     = (const float*)d_in[0];
    const float* in_w  = (const float*)d_in[1];
    const float* in_b  = (const float*)d_in[2];
    const float* hid_w = (const float*)d_in[3];
    const float* hid_b = (const float*)d_in[4];
    const float* res_w = (const float*)d_in[5];
    const float* res_b = (const float*)d_in[6];
    const float* mix_w = (const float*)d_in[7];
    const float* mix_b = (const float*)d_in[8];
    float* out = (float*)d_out;

    const size_t actN = (size_t)NB * NC * T_LEN;   // 8388608
    float* A0  = (float*)d_ws;
    float* A1  = A0 + actN;
    float* Wt  = A1 + actN;
    float* WrT = Wt + (size_t)NL * 3 * NC * 128;

    prep_kernel<<<4096, 256, 0, stream>>>(x, in_w, in_b, hid_w, res_w, mix_b,
                                          A0, Wt, WrT, out);

    static const int dils[NL] = {1, 2, 4, 8, 16, 32, 64, 128, 256,
                                 1, 2, 4, 8, 16, 32, 64, 128, 256};
    const float* src = A0;
    float* dst = A1;
    for (int i = 0; i < NL; i++) {
        layer_kernel<<<dim3(T_LEN / TILE_T, NB), 256, 0, stream>>>(
            src, dst,
            Wt + (size_t)i * 3 * NC * 128,
            hid_b + i * 128,
            WrT + (size_t)i * NC * NC,
            res_b + i * NC,
            mix_w + i * NC,
            out, dils[i]);
        const float* tmp = src;
        src = dst;
        dst = (float*)tmp;
    }
}

// Round 3
// 601.046 us; speedup vs baseline: 3.5019x; 3.5019x over previous
//
#include <hip/hip_runtime.h>
#include <hip/hip_bf16.h>
#include <math.h>

#define T_LEN 32768
#define NB 4
#define NC 64
#define NL 18
#define TILE_T 64

typedef __attribute__((ext_vector_type(8))) short s16x8;
typedef __attribute__((ext_vector_type(4))) float f32x4;
#define MFMA_BF16 __builtin_amdgcn_mfma_f32_16x16x32_bf16

__device__ inline unsigned short f2bf(float f) {
    unsigned u = __builtin_bit_cast(unsigned, f);
    unsigned r = u + 0x7FFFu + ((u >> 16) & 1u);
    return (unsigned short)(r >> 16);
}
__device__ inline unsigned pack_bf2(float a, float b) {
    return (unsigned)f2bf(a) | ((unsigned)f2bf(b) << 16);
}
__device__ inline float bf2f(unsigned short u) {
    return __builtin_bit_cast(float, (unsigned)u << 16);
}
__device__ inline float fast_sigmoid(float x) {
    return __builtin_amdgcn_rcpf(1.f + __expf(-x));
}
__device__ inline float fast_tanh(float x) {
    return 1.f - 2.f * __builtin_amdgcn_rcpf(1.f + __expf(2.f * x));
}

// ------------------------------------------------------------------
// prep: A0[b][t][c] = x*in_w+in_b ; Wh bf16 [L][128co][192K] (K=k*64+ci);
//       Wr bf16 [L][64co][64ci] ; out init = mix_b
// ------------------------------------------------------------------
__global__ void prep_kernel(const float* __restrict__ x,
                            const float* __restrict__ in_w,
                            const float* __restrict__ in_b,
                            const float* __restrict__ hid_w,
                            const float* __restrict__ res_w,
                            const float* __restrict__ mix_b,
                            float* __restrict__ A0,
                            unsigned short* __restrict__ Wh,
                            unsigned short* __restrict__ Wr,
                            float* __restrict__ out) {
    const int nAct = NB * T_LEN * NC;      // 8388608
    const int nW1 = NL * 128 * 192;        // 442368
    const int nW2 = NL * 64 * 64;          // 73728
    const int nOut = NB * T_LEN;           // 131072
    const int total = nAct + nW1 + nW2 + nOut;
    for (int gid = blockIdx.x * blockDim.x + threadIdx.x; gid < total;
         gid += gridDim.x * blockDim.x) {
        if (gid < nAct) {
            int c = gid & 63;
            int t = (gid >> 6) & (T_LEN - 1);
            int b = gid >> 21;
            A0[gid] = x[b * T_LEN + t] * in_w[c] + in_b[c];
        } else if (gid < nAct + nW1) {
            int q = gid - nAct;
            int K = q % 192;
            int co = (q / 192) & 127;
            int i = q / (192 * 128);
            int kt = K >> 6, ci = K & 63;
            Wh[q] = f2bf(hid_w[((i * 128 + co) * 64 + ci) * 3 + kt]);
        } else if (gid < nAct + nW1 + nW2) {
            int q = gid - (nAct + nW1);
            int c = q & 63, co = (q >> 6) & 63, i = q >> 12;
            Wr[q] = f2bf(res_w[(i * 64 + co) * 64 + c]);
        } else {
            out[gid - (nAct + nW1 + nW2)] = mix_b[0];
        }
    }
}

// ------------------------------------------------------------------
// fused layer, MFMA version. block = 256 thr = 4 waves; tile = (b, 64 t).
// wave w owns hid-co {16w..16w+15} u {64+16w..}, res-co {16w..16w+15}.
// ------------------------------------------------------------------
__launch_bounds__(256, 3)
__global__ void layer_kernel(const float* __restrict__ actIn,
                             float* __restrict__ actOut,
                             const unsigned short* __restrict__ Wh, // [128][192]
                             const float* __restrict__ hb,          // [128]
                             const unsigned short* __restrict__ Wr, // [64][64]
                             const float* __restrict__ rb,          // [64]
                             const float* __restrict__ mw,          // [64]
                             float* __restrict__ skip,              // [B][T]
                             int dil) {
    __shared__ uint4 Xs[3][512];   // 3 taps x [64t][64ci] bf16, XOR-swizzled
    __shared__ uint4 Gs[512];      // gated  [64t][64c]  bf16, XOR-swizzled

    const int tid = threadIdx.x;
    const int w = tid >> 6;
    const int l = tid & 63;
    const int lo = l & 15;
    const int hi = l >> 4;
    const int b = blockIdx.y;
    const int t0 = blockIdx.x * TILE_T;
    const float* actB = actIn + (size_t)b * T_LEN * NC;
    const int m0 = 16 * w;

    // ---- W fragments -> registers (L2-cached, reused all 6/2 K-slices) ----
    s16x8 AH[2][6];
    s16x8 AR[2];
#pragma unroll
    for (int mt = 0; mt < 2; mt++) {
        const unsigned short* wp = Wh + (size_t)(m0 + 64 * mt + lo) * 192;
#pragma unroll
        for (int s = 0; s < 6; s++)
            AH[mt][s] = *(const s16x8*)(wp + 32 * s + 8 * hi);
    }
#pragma unroll
    for (int s = 0; s < 2; s++)
        AR[s] = *(const s16x8*)(Wr + (size_t)(m0 + lo) * 64 + 32 * s + 8 * hi);

    float bA[4], bB[4], rbv[4];
#pragma unroll
    for (int r = 0; r < 4; r++) {
        bA[r] = hb[m0 + 4 * hi + r];
        bB[r] = hb[64 + m0 + 4 * hi + r];
        rbv[r] = rb[m0 + 4 * hi + r];
    }

    // ---- stage X taps: fp32 [t][c] -> bf16 LDS [t][ci], swizzled ----
#pragma unroll
    for (int k = 0; k < 3; k++) {
        const int off = (k - 2) * dil;
#pragma unroll
        for (int r = 0; r < 4; r++) {
            int p = r * 256 + tid;
            int row = p >> 4, c4 = p & 15;
            int st = t0 + row + off;
            float4 v = make_float4(0.f, 0.f, 0.f, 0.f);
            if (st >= 0) v = *(const float4*)(actB + (size_t)st * 64 + c4 * 4);
            unsigned u0 = pack_bf2(v.x, v.y);
            unsigned u1 = pack_bf2(v.z, v.w);
            int byte = (row * 128 + c4 * 8) ^ ((row & 7) << 4);
            ((uint2*)Xs)[(k * 8192 + byte) >> 3] = make_uint2(u0, u1);
        }
    }
    __syncthreads();

    // ---- hid GEMM: acc[mt][nt] over K=192 (3 taps x 64 ci) ----
    f32x4 acc[2][4];
#pragma unroll
    for (int mt = 0; mt < 2; mt++)
#pragma unroll
        for (int nt = 0; nt < 4; nt++)
            acc[mt][nt] = (f32x4){0.f, 0.f, 0.f, 0.f};

#pragma unroll
    for (int s = 0; s < 6; s++) {
        const int tap = s >> 1, half = s & 1;
#pragma unroll
        for (int nt = 0; nt < 4; nt++) {
            int t = 16 * nt + lo;
            int byte = (t * 128 + half * 64 + hi * 16) ^ ((t & 7) << 4);
            s16x8 bx = __builtin_bit_cast(
                s16x8, ((const uint4*)Xs)[(tap * 8192 + byte) >> 4]);
            acc[0][nt] = MFMA_BF16(AH[0][s], bx, acc[0][nt], 0, 0, 0);
            acc[1][nt] = MFMA_BF16(AH[1][s], bx, acc[1][nt], 0, 0, 0);
        }
    }

    // ---- gating -> Gs (bf16, swizzled). lane covers c = m0+4hi+r, t=16nt+lo
    const int c0 = m0 + 4 * hi;
#pragma unroll
    for (int nt = 0; nt < 4; nt++) {
        float g[4];
#pragma unroll
        for (int r = 0; r < 4; r++) {
            float hA = acc[0][nt][r] + bA[r];
            float hB = acc[1][nt][r] + bB[r];
            g[r] = fast_tanh(hA) * fast_sigmoid(hB);
        }
        int t = 16 * nt + lo;
        int byte = (t * 128 + c0 * 2) ^ ((t & 7) << 4);
        ((uint2*)Gs)[byte >> 3] =
            make_uint2(pack_bf2(g[0], g[1]), pack_bf2(g[2], g[3]));
    }
    __syncthreads();

    // ---- res GEMM over K=64 ----
    f32x4 acc2[4];
#pragma unroll
    for (int nt = 0; nt < 4; nt++) acc2[nt] = (f32x4){0.f, 0.f, 0.f, 0.f};
#pragma unroll
    for (int s = 0; s < 2; s++) {
#pragma unroll
        for (int nt = 0; nt < 4; nt++) {
            int t = 16 * nt + lo;
            int byte = (t * 128 + s * 64 + hi * 16) ^ ((t & 7) << 4);
            s16x8 bg =
                __builtin_bit_cast(s16x8, ((const uint4*)Gs)[byte >> 4]);
            acc2[nt] = MFMA_BF16(AR[s], bg, acc2[nt], 0, 0, 0);
        }
    }

    // ---- epilogue: actOut = res + rb + actIn (fp32 residual, L2-hot) ----
    float* outB = actOut + (size_t)b * T_LEN * NC;
#pragma unroll
    for (int nt = 0; nt < 4; nt++) {
        int t = 16 * nt + lo;
        size_t base = (size_t)(t0 + t) * 64 + c0;
        float4 inp = *(const float4*)(actB + base);
        float4 o;
        o.x = acc2[nt][0] + rbv[0] + inp.x;
        o.y = acc2[nt][1] + rbv[1] + inp.y;
        o.z = acc2[nt][2] + rbv[2] + inp.z;
        o.w = acc2[nt][3] + rbv[3] + inp.w;
        *(float4*)(outB + base) = o;
    }

    // ---- skip: out[b][t] += sum_c mw[c]*g[t][c]  (wave 0, one lane per t)
    if (tid < 64) {
        int t = tid;
        int swz = (t & 7) << 4;
        float s = 0.f;
#pragma unroll
        for (int j = 0; j < 8; j++) {
            uint4 gv = ((const uint4*)Gs)[((t * 128 + 16 * j) ^ swz) >> 4];
            unsigned uu[4] = {gv.x, gv.y, gv.z, gv.w};
#pragma unroll
            for (int e = 0; e < 4; e++) {
                s += bf2f((unsigned short)(uu[e] & 0xffff)) * mw[j * 8 + 2 * e];
                s += bf2f((unsigned short)(uu[e] >> 16)) * mw[j * 8 + 2 * e + 1];
            }
        }
        skip[(size_t)b * T_LEN + t0 + t] += s;
    }
}

// ------------------------------------------------------------------
extern "C" void kernel_launch(void* const* d_in, const int* in_sizes, int n_in,
                              void* d_out, int out_size, void* d_ws, size_t ws_size,
                              hipStream_t stream) {
    const float* x     = (const float*)d_in[0];
    const float* in_w  = (const float*)d_in[1];
    const float* in_b  = (const float*)d_in[2];
    const float* hid_w = (const float*)d_in[3];
    const float* hid_b = (const float*)d_in[4];
    const float* res_w = (const float*)d_in[5];
    const float* res_b = (const float*)d_in[6];
    const float* mix_w = (const float*)d_in[7];
    const float* mix_b = (const float*)d_in[8];
    float* out = (float*)d_out;

    const size_t actN = (size_t)NB * T_LEN * NC;  // 8388608
    float* A0 = (float*)d_ws;
    float* A1 = A0 + actN;
    unsigned short* Wh = (unsigned short*)(A1 + actN);
    unsigned short* Wr = Wh + (size_t)NL * 128 * 192;

    prep_kernel<<<2048, 256, 0, stream>>>(x, in_w, in_b, hid_w, res_w, mix_b,
                                          A0, Wh, Wr, out);

    static const int dils[NL] = {1, 2, 4, 8, 16, 32, 64, 128, 256,
                                 1, 2, 4, 8, 16, 32, 64, 128, 256};
    const float* src = A0;
    float* dst = A1;
    for (int i = 0; i < NL; i++) {
        layer_kernel<<<dim3(T_LEN / TILE_T, NB), 256, 0, stream>>>(
            src, dst,
            Wh + (size_t)i * 128 * 192,
            hid_b + (size_t)i * 128,
            Wr + (size_t)i * 64 * 64,
            res_b + (size_t)i * 64,
            mix_w + (size_t)i * 64,
            out, dils[i]);
        const float* tmp = src;
        src = dst;
        dst = (float*)tmp;
    }
}